// Round 1
// baseline (641.082 us; speedup 1.0000x reference)
//
#include <hip/hip_runtime.h>
#include <hip/hip_bf16.h>

typedef unsigned short u16;
typedef unsigned int   u32;
using bf16x8 = __attribute__((ext_vector_type(8))) short;
using f32x4  = __attribute__((ext_vector_type(4))) float;

#define AS1 __attribute__((address_space(1)))
#define AS3 __attribute__((address_space(3)))

static constexpr int S_   = 1024;
static constexpr int D_   = 4096;
static constexpr int H_   = 32;
static constexpr int KVH_ = 8;
static constexpr int HD_  = 128;
static constexpr int NQKV = H_*HD_ + 2*KVH_*HD_;   // 6144

__device__ __forceinline__ u16 f2bf(float f) {
  union { float f; u32 u; } v; v.f = f;
  u32 r = v.u + 0x7FFFu + ((v.u >> 16) & 1u);      // RTNE
  return (u16)(r >> 16);
}

// ---------------- x f32 -> bf16 ----------------
__global__ void k_convert(const float* __restrict__ src, u16* __restrict__ dst, int n4) {
  int i = blockIdx.x * blockDim.x + threadIdx.x;
  if (i >= n4) return;
  float4 v = ((const float4*)src)[i];
  ushort4 o;
  o.x = f2bf(v.x); o.y = f2bf(v.y); o.z = f2bf(v.z); o.w = f2bf(v.w);
  ((ushort4*)dst)[i] = o;
}

// ---------------- W [K][N] f32 -> Wt [N][K] bf16 ----------------
__global__ void k_transpose_w(const float* __restrict__ src, u16* __restrict__ dst,
                              int K, int N) {
  __shared__ float t[32][33];
  int k0 = blockIdx.y * 32, n0 = blockIdx.x * 32;
  int tx = threadIdx.x, ty = threadIdx.y;           // (32,8)
#pragma unroll
  for (int i = 0; i < 4; ++i)
    t[ty + i*8][tx] = src[(size_t)(k0 + ty + i*8) * N + n0 + tx];
  __syncthreads();
#pragma unroll
  for (int i = 0; i < 4; ++i)
    dst[(size_t)(n0 + ty + i*8) * K + k0 + tx] = f2bf(t[tx][ty + i*8]);
}

// ---------------- V [BG][S][HD] bf16 -> Vt [BG][HD][S] bf16 ----------------
__global__ void k_transpose_v(const u16* __restrict__ src, u16* __restrict__ dst) {
  __shared__ u16 t[32][33];
  int bg = blockIdx.z;
  int s0 = blockIdx.x * 32, h0 = blockIdx.y * 32;
  src += (size_t)bg * S_ * HD_;
  dst += (size_t)bg * S_ * HD_;
  int tx = threadIdx.x, ty = threadIdx.y;
#pragma unroll
  for (int i = 0; i < 4; ++i)
    t[ty + i*8][tx] = src[(size_t)(s0 + ty + i*8) * HD_ + h0 + tx];
  __syncthreads();
#pragma unroll
  for (int i = 0; i < 4; ++i)
    dst[(size_t)(h0 + ty + i*8) * S_ + s0 + tx] = t[tx][ty + i*8];
}

// ---------------- RoPE tables: cos/sin [S][64] f32 ----------------
__global__ void k_rope(const int* __restrict__ sidx, float* __restrict__ cosd,
                       float* __restrict__ sind) {
  int i = blockIdx.x * blockDim.x + threadIdx.x;    // S*64
  int s = i >> 6, d = i & 63;
  float pos  = (float)sidx[s];
  float invf = expf(-0.21586735246819178f * (float)d);  // 1e6^(-d/64)
  float ph   = pos * invf;
  cosd[i] = cosf(ph);
  sind[i] = sinf(ph);
}

// ---------------- 128x128 bf16 GEMM: C[M][N] = A[M][K] * Bt[N][K]^T ----------------
__global__ __launch_bounds__(256) void k_gemm(
    const u16* __restrict__ A, const u16* __restrict__ Bt,
    float* __restrict__ C, int M, int N, int K)
{
  __shared__ char As[16384];
  __shared__ char Bs[16384];
  int tid = threadIdx.x, lane = tid & 63, wid = tid >> 6;
  int l15 = lane & 15, l4 = lane >> 4;
  int m0 = blockIdx.y * 128, n0 = blockIdx.x * 128;
  int wr = wid >> 1, wc = wid & 1;
  f32x4 acc[4][4];
#pragma unroll
  for (int i = 0; i < 4; ++i)
#pragma unroll
    for (int j = 0; j < 4; ++j) acc[i][j] = (f32x4){0.f,0.f,0.f,0.f};

  // staging map: LDS byte o = chunk*1024 + lane*16; row = o>>7; stored slot ss=(o>>4)&7
  // holds source slot ss^(row&7)  (XOR swizzle, both-sides)
  int arow[4], aslot[4];
#pragma unroll
  for (int q = 0; q < 4; ++q) {
    int o = (wid*4 + q)*1024 + lane*16;
    int row = o >> 7, ss = (o >> 4) & 7;
    arow[q] = row; aslot[q] = ss ^ (row & 7);
  }

  for (int kt = 0; kt < K; kt += 64) {
#pragma unroll
    for (int q = 0; q < 4; ++q) {
      __builtin_amdgcn_global_load_lds(
          (AS1 void*)(A  + (size_t)(m0 + arow[q]) * K + kt + aslot[q]*8),
          (AS3 void*)(As + (wid*4 + q)*1024), 16, 0, 0);
      __builtin_amdgcn_global_load_lds(
          (AS1 void*)(Bt + (size_t)(n0 + arow[q]) * K + kt + aslot[q]*8),
          (AS3 void*)(Bs + (wid*4 + q)*1024), 16, 0, 0);
    }
    __syncthreads();   // compiler drains vmcnt before s_barrier
#pragma unroll
    for (int kk = 0; kk < 2; ++kk) {
      int ks = kk*4 + l4;
      bf16x8 af[4], bfv[4];
#pragma unroll
      for (int i = 0; i < 4; ++i) {
        int row = wr*64 + i*16 + l15;
        af[i] = *(const bf16x8*)(As + row*128 + ((ks ^ (row & 7)) << 4));
      }
#pragma unroll
      for (int j = 0; j < 4; ++j) {
        int row = wc*64 + j*16 + l15;
        bfv[j] = *(const bf16x8*)(Bs + row*128 + ((ks ^ (row & 7)) << 4));
      }
#pragma unroll
      for (int i = 0; i < 4; ++i)
#pragma unroll
        for (int j = 0; j < 4; ++j)
          acc[i][j] = __builtin_amdgcn_mfma_f32_16x16x32_bf16(af[i], bfv[j], acc[i][j], 0, 0, 0);
    }
    __syncthreads();
  }
#pragma unroll
  for (int i = 0; i < 4; ++i)
#pragma unroll
    for (int j = 0; j < 4; ++j) {
      int r0 = m0 + wr*64 + i*16 + l4*4;
      int c0 = n0 + wc*64 + j*16 + l15;
#pragma unroll
      for (int r = 0; r < 4; ++r)
        C[(size_t)(r0 + r) * N + c0] = acc[i][j][r];
    }
}

// ---------------- bias + RoPE + pack to [B][H][S][HD] bf16 ----------------
__global__ void k_pack(const float* __restrict__ Cq,
                       const float* __restrict__ bq, const float* __restrict__ bk,
                       const float* __restrict__ bv,
                       const float* __restrict__ cosd, const float* __restrict__ sind,
                       u16* __restrict__ qb, u16* __restrict__ kb, u16* __restrict__ vb) {
  int t = blockIdx.x;
  int b = t >> 10, s = t & 1023;
  const float* row = Cq + (size_t)t * NQKV;
  const float* cs = cosd + s*64;
  const float* sn = sind + s*64;
  const float qscale = 0.08838834764831845f;  // 1/sqrt(HD)
  for (int c = threadIdx.x; c < H_*HD_; c += blockDim.x) {
    int h = c >> 7, d = c & 127;
    float v = row[c] + bq[c];
    float o;
    if (d < 64) { float p = row[c + 64] + bq[c + 64]; o = v*cs[d]    - p*sn[d]; }
    else        { float p = row[c - 64] + bq[c - 64]; o = v*cs[d-64] + p*sn[d-64]; }
    qb[(((size_t)b*H_ + h)*S_ + s)*HD_ + d] = f2bf(o * qscale);
  }
  for (int c = threadIdx.x; c < KVH_*HD_; c += blockDim.x) {
    int g = c >> 7, d = c & 127;
    float v = row[H_*HD_ + c] + bk[c];
    float o;
    if (d < 64) { float p = row[H_*HD_ + c + 64] + bk[c + 64]; o = v*cs[d]    - p*sn[d]; }
    else        { float p = row[H_*HD_ + c - 64] + bk[c - 64]; o = v*cs[d-64] + p*sn[d-64]; }
    size_t idx = (((size_t)b*KVH_ + g)*S_ + s)*HD_ + d;
    kb[idx] = f2bf(o);
    vb[idx] = f2bf(row[H_*HD_ + KVH_*HD_ + c] + bv[c]);
  }
}

// ---------------- causal GQA flash attention ----------------
// grid (S/64, H, B), 4 waves; wave owns 16 q-rows. K/V direct from global (L2-resident).
__global__ __launch_bounds__(256) void k_attn(
    const u16* __restrict__ Q, const u16* __restrict__ Kc,
    const u16* __restrict__ Vt, u16* __restrict__ AO)
{
  int qtile = blockIdx.x, h = blockIdx.y, b = blockIdx.z;
  int g = h >> 2;
  int lane = threadIdx.x & 63, w = threadIdx.x >> 6;
  int l15 = lane & 15, l4 = lane >> 4;
  int qrow0 = qtile * 64 + w * 16;
  const u16* Qp = Q  + (((size_t)b*H_   + h) * S_ + qrow0) * HD_;
  const u16* Kp = Kc + ((size_t)b*KVH_ + g) * S_ * HD_;
  const u16* Vp = Vt + ((size_t)b*KVH_ + g) * (size_t)HD_ * S_;   // [HD][S]
  __shared__ u16 Pl[4][1024];   // per-wave 16x64 bf16 P tile, XOR-swizzled
  char* Pw = (char*)&Pl[w][0];

  bf16x8 qf[4];
#pragma unroll
  for (int kc = 0; kc < 4; ++kc)
    qf[kc] = *(const bf16x8*)(Qp + l15*HD_ + kc*32 + l4*8);

  f32x4 o[8];
#pragma unroll
  for (int n = 0; n < 8; ++n) o[n] = (f32x4){0.f,0.f,0.f,0.f};
  float mrow[4] = {-3e38f,-3e38f,-3e38f,-3e38f};
  float lrow[4] = {0.f,0.f,0.f,0.f};

  for (int kv = 0; kv <= qtile; ++kv) {
    int kvb = kv * 64;
    f32x4 sc[4];
#pragma unroll
    for (int ct = 0; ct < 4; ++ct) {
      f32x4 s4 = (f32x4){0.f,0.f,0.f,0.f};
#pragma unroll
      for (int kc = 0; kc < 4; ++kc) {
        bf16x8 kf = *(const bf16x8*)(Kp + (size_t)(kvb + ct*16 + l15)*HD_ + kc*32 + l4*8);
        s4 = __builtin_amdgcn_mfma_f32_16x16x32_bf16(qf[kc], kf, s4, 0, 0, 0);
      }
      sc[ct] = s4;
    }
    if (kv == qtile) {
#pragma unroll
      for (int ct = 0; ct < 4; ++ct)
#pragma unroll
        for (int r = 0; r < 4; ++r) {
          int col = kvb + ct*16 + l15;
          int rw  = qrow0 + l4*4 + r;
          if (col > rw) sc[ct][r] = -1e9f;
        }
    }
    float f[4];
#pragma unroll
    for (int r = 0; r < 4; ++r) {
      float mx = fmaxf(fmaxf(sc[0][r], sc[1][r]), fmaxf(sc[2][r], sc[3][r]));
      mx = fmaxf(mx, __shfl_xor(mx, 1));
      mx = fmaxf(mx, __shfl_xor(mx, 2));
      mx = fmaxf(mx, __shfl_xor(mx, 4));
      mx = fmaxf(mx, __shfl_xor(mx, 8));
      float nm = fmaxf(mrow[r], mx);
      f[r] = __expf(mrow[r] - nm);
      mrow[r] = nm;
    }
    float rs[4] = {0.f,0.f,0.f,0.f};
#pragma unroll
    for (int ct = 0; ct < 4; ++ct)
#pragma unroll
      for (int r = 0; r < 4; ++r) {
        float p = __expf(sc[ct][r] - mrow[r]);
        rs[r] += p;
        int row = l4*4 + r, col = ct*16 + l15;
        int byte = row*128 + (((col >> 3) ^ (row & 7)) << 4) + (col & 7)*2;
        *(u16*)(Pw + byte) = f2bf(p);
      }
#pragma unroll
    for (int r = 0; r < 4; ++r) {
      float sum = rs[r];
      sum += __shfl_xor(sum, 1);
      sum += __shfl_xor(sum, 2);
      sum += __shfl_xor(sum, 4);
      sum += __shfl_xor(sum, 8);
      lrow[r] = lrow[r]*f[r] + sum;
    }
#pragma unroll
    for (int n = 0; n < 8; ++n)
#pragma unroll
      for (int r = 0; r < 4; ++r) o[n][r] *= f[r];
    __syncthreads();
#pragma unroll
    for (int kk = 0; kk < 2; ++kk) {
      int prow = l15, pslot = kk*4 + l4;
      bf16x8 pf = *(const bf16x8*)(Pw + prow*128 + ((pslot ^ (prow & 7)) << 4));
#pragma unroll
      for (int n = 0; n < 8; ++n) {
        bf16x8 vf = *(const bf16x8*)(Vp + (size_t)(n*16 + l15)*S_ + kvb + kk*32 + l4*8);
        o[n] = __builtin_amdgcn_mfma_f32_16x16x32_bf16(pf, vf, o[n], 0, 0, 0);
      }
    }
    __syncthreads();
  }
#pragma unroll
  for (int n = 0; n < 8; ++n)
#pragma unroll
    for (int r = 0; r < 4; ++r) {
      int srow = qrow0 + l4*4 + r;
      AO[((size_t)b*S_ + srow)*(size_t)(H_*HD_) + h*HD_ + n*16 + l15] = f2bf(o[n][r] / lrow[r]);
    }
}

extern "C" void kernel_launch(void* const* d_in, const int* in_sizes, int n_in,
                              void* d_out, int out_size, void* d_ws, size_t ws_size,
                              hipStream_t stream) {
  (void)in_sizes; (void)n_in; (void)out_size; (void)ws_size;
  const float* x   = (const float*)d_in[0];
  const int*   sid = (const int*)  d_in[1];
  // d_in[2] = cache (dead), d_in[3] = mask (dead: causal re-derived)
  const float* Wq  = (const float*)d_in[4];
  const float* bq  = (const float*)d_in[5];
  const float* Wk  = (const float*)d_in[6];
  const float* bk  = (const float*)d_in[7];
  const float* Wv  = (const float*)d_in[8];
  const float* bv  = (const float*)d_in[9];
  const float* Wo  = (const float*)d_in[10];
  float* out = (float*)d_out;

  char* ws = (char*)d_ws;
  u16*   xb   = (u16*)  (ws);                    // 16,777,216 B (aliased by AO later)
  u16*   WB   = (u16*)  (ws + 16777216);         // 50,331,648 B  [6144][4096]
  u16*   WoT  = (u16*)  (ws + 67108864);         // 33,554,432 B  [4096][4096]
  float* Cq   = (float*)(ws + 100663296);        // 50,331,648 B  [2048][6144]
  u16*   qb   = (u16*)  (ws + 150994944);        // 16,777,216 B  [B][H][S][HD]
  u16*   kb   = (u16*)  (ws + 167772160);        //  4,194,304 B  [B][KVH][S][HD]
  u16*   vb   = (u16*)  (ws + 171966464);        //  4,194,304 B
  u16*   VT   = (u16*)  (ws + 176160768);        //  4,194,304 B  [B][KVH][HD][S]
  float* cosd = (float*)(ws + 180355072);        //    262,144 B
  float* sind = (float*)(ws + 180617216);        //    262,144 B  (total ~181 MB)
  u16*   AO   = xb;                              // attention output reuses xb

  dim3 tb(32, 8);
  k_convert<<<8192, 256, 0, stream>>>(x, xb, (2048*4096)/4);
  k_transpose_w<<<dim3(128,128), tb, 0, stream>>>(Wq, WB, 4096, 4096);
  k_transpose_w<<<dim3( 32,128), tb, 0, stream>>>(Wk, WB + (size_t)4096*4096, 4096, 1024);
  k_transpose_w<<<dim3( 32,128), tb, 0, stream>>>(Wv, WB + (size_t)5120*4096, 4096, 1024);
  k_transpose_w<<<dim3(128,128), tb, 0, stream>>>(Wo, WoT, 4096, 4096);
  k_rope<<<256, 256, 0, stream>>>(sid, cosd, sind);
  k_gemm<<<dim3(48,16), 256, 0, stream>>>(xb, WB, Cq, 2048, NQKV, 4096);
  k_pack<<<2048, 256, 0, stream>>>(Cq, bq, bk, bv, cosd, sind, qb, kb, vb);
  k_transpose_v<<<dim3(32,4,16), tb, 0, stream>>>(vb, VT);
  k_attn<<<dim3(16,32,2), 256, 0, stream>>>(qb, kb, VT, AO);
  k_gemm<<<dim3(32,16), 256, 0, stream>>>(AO, WoT, out, 2048, 4096, 4096);
}

// Round 2
// 542.031 us; speedup vs baseline: 1.1827x; 1.1827x over previous
//
#include <hip/hip_runtime.h>
#include <hip/hip_bf16.h>

typedef unsigned short u16;
typedef unsigned int   u32;
using bf16x8 = __attribute__((ext_vector_type(8))) short;
using f32x4  = __attribute__((ext_vector_type(4))) float;

#define AS1 __attribute__((address_space(1)))
#define AS3 __attribute__((address_space(3)))

static constexpr int S_   = 1024;
static constexpr int D_   = 4096;
static constexpr int H_   = 32;
static constexpr int KVH_ = 8;
static constexpr int HD_  = 128;
static constexpr int NQKV = H_*HD_ + 2*KVH_*HD_;   // 6144

__device__ __forceinline__ u16 f2bf(float f) {
  union { float f; u32 u; } v; v.f = f;
  u32 r = v.u + 0x7FFFu + ((v.u >> 16) & 1u);      // RTNE
  return (u16)(r >> 16);
}

// ---------------- x f32 -> bf16 ----------------
__global__ void k_convert(const float* __restrict__ src, u16* __restrict__ dst, int n4) {
  int i = blockIdx.x * blockDim.x + threadIdx.x;
  if (i >= n4) return;
  float4 v = ((const float4*)src)[i];
  ushort4 o;
  o.x = f2bf(v.x); o.y = f2bf(v.y); o.z = f2bf(v.z); o.w = f2bf(v.w);
  ((ushort4*)dst)[i] = o;
}

// ---------------- W [K][N] f32 -> Wt [N][K] bf16 ----------------
__global__ void k_transpose_w(const float* __restrict__ src, u16* __restrict__ dst,
                              int K, int N) {
  __shared__ float t[32][33];
  int k0 = blockIdx.y * 32, n0 = blockIdx.x * 32;
  int tx = threadIdx.x, ty = threadIdx.y;           // (32,8)
#pragma unroll
  for (int i = 0; i < 4; ++i)
    t[ty + i*8][tx] = src[(size_t)(k0 + ty + i*8) * N + n0 + tx];
  __syncthreads();
#pragma unroll
  for (int i = 0; i < 4; ++i)
    dst[(size_t)(n0 + ty + i*8) * K + k0 + tx] = f2bf(t[tx][ty + i*8]);
}

// ---------------- V [BG][S][HD] bf16 -> Vt [BG][HD][S] bf16 ----------------
__global__ void k_transpose_v(const u16* __restrict__ src, u16* __restrict__ dst) {
  __shared__ u16 t[32][33];
  int bg = blockIdx.z;
  int s0 = blockIdx.x * 32, h0 = blockIdx.y * 32;
  src += (size_t)bg * S_ * HD_;
  dst += (size_t)bg * S_ * HD_;
  int tx = threadIdx.x, ty = threadIdx.y;
#pragma unroll
  for (int i = 0; i < 4; ++i)
    t[ty + i*8][tx] = src[(size_t)(s0 + ty + i*8) * HD_ + h0 + tx];
  __syncthreads();
#pragma unroll
  for (int i = 0; i < 4; ++i)
    dst[(size_t)(h0 + ty + i*8) * S_ + s0 + tx] = t[tx][ty + i*8];
}

// ---------------- RoPE tables: cos/sin [S][64] f32 ----------------
__global__ void k_rope(const int* __restrict__ sidx, float* __restrict__ cosd,
                       float* __restrict__ sind) {
  int i = blockIdx.x * blockDim.x + threadIdx.x;    // S*64
  int s = i >> 6, d = i & 63;
  float pos  = (float)sidx[s];
  float invf = expf(-0.21586735246819178f * (float)d);  // 1e6^(-d/64)
  float ph   = pos * invf;
  cosd[i] = cosf(ph);
  sind[i] = sinf(ph);
}

// ---------------- 128x128 bf16 GEMM: C[M][N] = A[M][K] * Bt[N][K]^T ----------------
__global__ __launch_bounds__(256) void k_gemm(
    const u16* __restrict__ A, const u16* __restrict__ Bt,
    float* __restrict__ C, int M, int N, int K)
{
  __shared__ char As[16384];
  __shared__ char Bs[16384];
  int tid = threadIdx.x, lane = tid & 63, wid = tid >> 6;
  int l15 = lane & 15, l4 = lane >> 4;
  int m0 = blockIdx.y * 128, n0 = blockIdx.x * 128;
  int wr = wid >> 1, wc = wid & 1;
  f32x4 acc[4][4];
#pragma unroll
  for (int i = 0; i < 4; ++i)
#pragma unroll
    for (int j = 0; j < 4; ++j) acc[i][j] = (f32x4){0.f,0.f,0.f,0.f};

  int arow[4], aslot[4];
#pragma unroll
  for (int q = 0; q < 4; ++q) {
    int o = (wid*4 + q)*1024 + lane*16;
    int row = o >> 7, ss = (o >> 4) & 7;
    arow[q] = row; aslot[q] = ss ^ (row & 7);
  }

  for (int kt = 0; kt < K; kt += 64) {
#pragma unroll
    for (int q = 0; q < 4; ++q) {
      __builtin_amdgcn_global_load_lds(
          (AS1 void*)(A  + (size_t)(m0 + arow[q]) * K + kt + aslot[q]*8),
          (AS3 void*)(As + (wid*4 + q)*1024), 16, 0, 0);
      __builtin_amdgcn_global_load_lds(
          (AS1 void*)(Bt + (size_t)(n0 + arow[q]) * K + kt + aslot[q]*8),
          (AS3 void*)(Bs + (wid*4 + q)*1024), 16, 0, 0);
    }
    __syncthreads();
#pragma unroll
    for (int kk = 0; kk < 2; ++kk) {
      int ks = kk*4 + l4;
      bf16x8 af[4], bfv[4];
#pragma unroll
      for (int i = 0; i < 4; ++i) {
        int row = wr*64 + i*16 + l15;
        af[i] = *(const bf16x8*)(As + row*128 + ((ks ^ (row & 7)) << 4));
      }
#pragma unroll
      for (int j = 0; j < 4; ++j) {
        int row = wc*64 + j*16 + l15;
        bfv[j] = *(const bf16x8*)(Bs + row*128 + ((ks ^ (row & 7)) << 4));
      }
#pragma unroll
      for (int i = 0; i < 4; ++i)
#pragma unroll
        for (int j = 0; j < 4; ++j)
          acc[i][j] = __builtin_amdgcn_mfma_f32_16x16x32_bf16(af[i], bfv[j], acc[i][j], 0, 0, 0);
    }
    __syncthreads();
  }
#pragma unroll
  for (int i = 0; i < 4; ++i)
#pragma unroll
    for (int j = 0; j < 4; ++j) {
      int r0 = m0 + wr*64 + i*16 + l4*4;
      int c0 = n0 + wc*64 + j*16 + l15;
#pragma unroll
      for (int r = 0; r < 4; ++r)
        C[(size_t)(r0 + r) * N + c0] = acc[i][j][r];
    }
}

// ---------------- bias + RoPE + pack to [B][H][S][HD] bf16 ----------------
__global__ void k_pack(const float* __restrict__ Cq,
                       const float* __restrict__ bq, const float* __restrict__ bk,
                       const float* __restrict__ bv,
                       const float* __restrict__ cosd, const float* __restrict__ sind,
                       u16* __restrict__ qb, u16* __restrict__ kb, u16* __restrict__ vb) {
  int t = blockIdx.x;
  int b = t >> 10, s = t & 1023;
  const float* row = Cq + (size_t)t * NQKV;
  const float* cs = cosd + s*64;
  const float* sn = sind + s*64;
  const float qscale = 0.08838834764831845f;  // 1/sqrt(HD)
  for (int c = threadIdx.x; c < H_*HD_; c += blockDim.x) {
    int h = c >> 7, d = c & 127;
    float v = row[c] + bq[c];
    float o;
    if (d < 64) { float p = row[c + 64] + bq[c + 64]; o = v*cs[d]    - p*sn[d]; }
    else        { float p = row[c - 64] + bq[c - 64]; o = v*cs[d-64] + p*sn[d-64]; }
    qb[(((size_t)b*H_ + h)*S_ + s)*HD_ + d] = f2bf(o * qscale);
  }
  for (int c = threadIdx.x; c < KVH_*HD_; c += blockDim.x) {
    int g = c >> 7, d = c & 127;
    float v = row[H_*HD_ + c] + bk[c];
    float o;
    if (d < 64) { float p = row[H_*HD_ + c + 64] + bk[c + 64]; o = v*cs[d]    - p*sn[d]; }
    else        { float p = row[H_*HD_ + c - 64] + bk[c - 64]; o = v*cs[d-64] + p*sn[d-64]; }
    size_t idx = (((size_t)b*KVH_ + g)*S_ + s)*HD_ + d;
    kb[idx] = f2bf(o);
    vb[idx] = f2bf(row[H_*HD_ + KVH_*HD_ + c] + bv[c]);
  }
}

// ---------------- causal GQA flash attention ----------------
// One 64-row q-tile, processed by 4 independent waves (16 rows each).
// NO barriers: each wave's P tile lives in its own LDS slice.
__device__ __forceinline__ void attn_tile(
    int qtile, const u16* __restrict__ Qh, const u16* __restrict__ Kp,
    const u16* __restrict__ Vp, u16* __restrict__ AOh,
    int lane, int w, char* Pw)
{
  int l15 = lane & 15, l4 = lane >> 4;
  int qrow0 = qtile * 64 + w * 16;
  const u16* Qp = Qh + (size_t)qrow0 * HD_;

  bf16x8 qf[4];
#pragma unroll
  for (int kc = 0; kc < 4; ++kc)
    qf[kc] = *(const bf16x8*)(Qp + l15*HD_ + kc*32 + l4*8);

  f32x4 o[8];
#pragma unroll
  for (int n = 0; n < 8; ++n) o[n] = (f32x4){0.f,0.f,0.f,0.f};
  float mrow[4] = {-3e38f,-3e38f,-3e38f,-3e38f};
  float lrow[4] = {0.f,0.f,0.f,0.f};

  for (int kv = 0; kv <= qtile; ++kv) {
    int kvb = kv * 64;
    f32x4 sc[4];
#pragma unroll
    for (int ct = 0; ct < 4; ++ct) {
      f32x4 s4 = (f32x4){0.f,0.f,0.f,0.f};
#pragma unroll
      for (int kc = 0; kc < 4; ++kc) {
        bf16x8 kf = *(const bf16x8*)(Kp + (size_t)(kvb + ct*16 + l15)*HD_ + kc*32 + l4*8);
        s4 = __builtin_amdgcn_mfma_f32_16x16x32_bf16(qf[kc], kf, s4, 0, 0, 0);
      }
      sc[ct] = s4;
    }
    if (kv == qtile) {
#pragma unroll
      for (int ct = 0; ct < 4; ++ct)
#pragma unroll
        for (int r = 0; r < 4; ++r) {
          int col = kvb + ct*16 + l15;
          int rw  = qrow0 + l4*4 + r;
          if (col > rw) sc[ct][r] = -1e9f;
        }
    }
    float f[4];
#pragma unroll
    for (int r = 0; r < 4; ++r) {
      float mx = fmaxf(fmaxf(sc[0][r], sc[1][r]), fmaxf(sc[2][r], sc[3][r]));
      mx = fmaxf(mx, __shfl_xor(mx, 1));
      mx = fmaxf(mx, __shfl_xor(mx, 2));
      mx = fmaxf(mx, __shfl_xor(mx, 4));
      mx = fmaxf(mx, __shfl_xor(mx, 8));
      float nm = fmaxf(mrow[r], mx);
      f[r] = __expf(mrow[r] - nm);
      mrow[r] = nm;
    }
    float rs[4] = {0.f,0.f,0.f,0.f};
#pragma unroll
    for (int ct = 0; ct < 4; ++ct)
#pragma unroll
      for (int r = 0; r < 4; ++r) {
        float p = __expf(sc[ct][r] - mrow[r]);
        rs[r] += p;
        int row = l4*4 + r, col = ct*16 + l15;
        int byte = row*128 + (((col >> 3) ^ (row & 7)) << 4) + (col & 7)*2;
        *(u16*)(Pw + byte) = f2bf(p);
      }
#pragma unroll
    for (int r = 0; r < 4; ++r) {
      float sum = rs[r];
      sum += __shfl_xor(sum, 1);
      sum += __shfl_xor(sum, 2);
      sum += __shfl_xor(sum, 4);
      sum += __shfl_xor(sum, 8);
      lrow[r] = lrow[r]*f[r] + sum;
    }
#pragma unroll
    for (int n = 0; n < 8; ++n)
#pragma unroll
      for (int r = 0; r < 4; ++r) o[n][r] *= f[r];
    // P tile is same-wave private: compiler inserts lgkmcnt for the ds deps.
#pragma unroll
    for (int kk = 0; kk < 2; ++kk) {
      int prow = l15, pslot = kk*4 + l4;
      bf16x8 pf = *(const bf16x8*)(Pw + prow*128 + ((pslot ^ (prow & 7)) << 4));
#pragma unroll
      for (int n = 0; n < 8; ++n) {
        bf16x8 vf = *(const bf16x8*)(Vp + (size_t)(n*16 + l15)*S_ + kvb + kk*32 + l4*8);
        o[n] = __builtin_amdgcn_mfma_f32_16x16x32_bf16(pf, vf, o[n], 0, 0, 0);
      }
    }
  }
#pragma unroll
  for (int n = 0; n < 8; ++n)
#pragma unroll
    for (int r = 0; r < 4; ++r) {
      int srow = qrow0 + l4*4 + r;
      AOh[(size_t)srow * (H_*HD_) + n*16 + l15] = f2bf(o[n][r] / lrow[r]);
    }
}

// grid (8, H, B): block handles q-tiles {t, 15-t} -> 17 kv-units each (balanced).
__global__ __launch_bounds__(256) void k_attn(
    const u16* __restrict__ Q, const u16* __restrict__ Kc,
    const u16* __restrict__ Vt, u16* __restrict__ AO)
{
  int t = blockIdx.x, h = blockIdx.y, b = blockIdx.z;
  int g = h >> 2;
  int lane = threadIdx.x & 63, w = threadIdx.x >> 6;
  const u16* Qh = Q  + ((size_t)b*H_   + h) * S_ * HD_;
  const u16* Kp = Kc + ((size_t)b*KVH_ + g) * S_ * HD_;
  const u16* Vp = Vt + ((size_t)b*KVH_ + g) * (size_t)HD_ * S_;   // [HD][S]
  u16* AOh = AO + ((size_t)b*S_) * (H_*HD_) + h*HD_;
  __shared__ u16 Pl[4][1024];
  char* Pw = (char*)&Pl[w][0];

  attn_tile(t,      Qh, Kp, Vp, AOh, lane, w, Pw);
  attn_tile(15 - t, Qh, Kp, Vp, AOh, lane, w, Pw);
}

extern "C" void kernel_launch(void* const* d_in, const int* in_sizes, int n_in,
                              void* d_out, int out_size, void* d_ws, size_t ws_size,
                              hipStream_t stream) {
  (void)in_sizes; (void)n_in; (void)out_size; (void)ws_size;
  const float* x   = (const float*)d_in[0];
  const int*   sid = (const int*)  d_in[1];
  // d_in[2] = cache (dead), d_in[3] = mask (dead: causal re-derived)
  const float* Wq  = (const float*)d_in[4];
  const float* bq  = (const float*)d_in[5];
  const float* Wk  = (const float*)d_in[6];
  const float* bk  = (const float*)d_in[7];
  const float* Wv  = (const float*)d_in[8];
  const float* bv  = (const float*)d_in[9];
  const float* Wo  = (const float*)d_in[10];
  float* out = (float*)d_out;

  char* ws = (char*)d_ws;
  u16*   xb   = (u16*)  (ws);                    // 16 MB (aliased by AO later)
  u16*   WB   = (u16*)  (ws + 16777216);         // 48 MB  [6144][4096]
  u16*   WoT  = (u16*)  (ws + 67108864);         // 32 MB  [4096][4096]
  float* Cq   = (float*)(ws + 100663296);        // 48 MB  [2048][6144]
  u16*   qb   = (u16*)  (ws + 150994944);        // 16 MB  [B][H][S][HD]
  u16*   kb   = (u16*)  (ws + 167772160);        //  4 MB  [B][KVH][S][HD]
  u16*   vb   = (u16*)  (ws + 171966464);        //  4 MB
  u16*   VT   = (u16*)  (ws + 176160768);        //  4 MB  [B][KVH][HD][S]
  float* cosd = (float*)(ws + 180355072);        // 256 KB
  float* sind = (float*)(ws + 180617216);        // 256 KB (total ~181 MB)
  u16*   AO   = xb;                              // attention output reuses xb

  dim3 tb(32, 8);
  k_convert<<<8192, 256, 0, stream>>>(x, xb, (2048*4096)/4);
  k_transpose_w<<<dim3(128,128), tb, 0, stream>>>(Wq, WB, 4096, 4096);
  k_transpose_w<<<dim3( 32,128), tb, 0, stream>>>(Wk, WB + (size_t)4096*4096, 4096, 1024);
  k_transpose_w<<<dim3( 32,128), tb, 0, stream>>>(Wv, WB + (size_t)5120*4096, 4096, 1024);
  k_transpose_w<<<dim3(128,128), tb, 0, stream>>>(Wo, WoT, 4096, 4096);
  k_rope<<<256, 256, 0, stream>>>(sid, cosd, sind);
  k_gemm<<<dim3(48,16), 256, 0, stream>>>(xb, WB, Cq, 2048, NQKV, 4096);
  k_pack<<<2048, 256, 0, stream>>>(Cq, bq, bk, bv, cosd, sind, qb, kb, vb);
  k_transpose_v<<<dim3(32,4,16), tb, 0, stream>>>(vb, VT);
  k_attn<<<dim3(8,32,2), 256, 0, stream>>>(qb, kb, VT, AO);
  k_gemm<<<dim3(32,16), 256, 0, stream>>>(AO, WoT, out, 2048, 4096, 4096);
}